// Round 1
// baseline (59.920 us; speedup 1.0000x reference)
//
#include <hip/hip_runtime.h>
#include <math.h>

#define NB   8
#define NC   2048
#define HH   128
#define WW   128
#define NTQ  4096
#define EPSF 1e-6f

#define QPB  64          // queries per block
#define SUBS 4           // context sub-scans (one per wave)
#define CPS  (NC / SUBS) // 512 points per sub-scan
#define BLK  256

#define FMAXV 3.402823466e+38f

__global__ __launch_bounds__(BLK) void interp_enc_kernel(
    const float* __restrict__ xc_off,  // (B,NC,2)
    const float* __restrict__ yc_off,  // (B,NC,1)
    const float* __restrict__ xc_on,   // (B,H,W,2)
    const float* __restrict__ yc_on,   // (B,H,W,1)
    const float* __restrict__ xt,      // (B,NT,2)
    const float* __restrict__ mix_w,   // (2,1)
    const float* __restrict__ mix_b,   // (1,)
    float* __restrict__ out)           // (B,NT,1)
{
#pragma clang fp contract(off)
    __shared__ float2 spts[NC];          // 16 KB
    __shared__ float  sval[NC];          // 8 KB
    __shared__ float  sgx[HH];
    __shared__ float  sgy[WW];
    __shared__ float  cd[SUBS][QPB][3];  // 3 KB
    __shared__ int    ci[SUBS][QPB][3];  // 3 KB
    __shared__ float  red[BLK];          // 1 KB

    const int tid   = threadIdx.x;
    const int b     = blockIdx.x >> 6;          // 64 blocks per batch
    const int qbase = (blockIdx.x & 63) * QPB;

    // ---- stage context (points + values) to LDS; partial sums for mean fill
    const float2* xcb = (const float2*)(xc_off + (size_t)b * NC * 2);
    const float*  ycb = yc_off + (size_t)b * NC;
    float psum = 0.f;
    for (int k = tid; k < NC; k += BLK) {
        float2 p = xcb[k];
        spts[k] = p;
        float v = ycb[k];
        sval[k] = v;
        psum += v;
    }
    red[tid] = psum;

    // ---- stage grid axes (read the actual linspace values from the input)
    const float* xob = xc_on + (size_t)b * HH * WW * 2;
    if (tid < HH) {
        sgx[tid] = xob[(size_t)tid * WW * 2];       // xc_on[b, i, 0, 0]
    } else if (tid < HH + WW) {
        int j = tid - HH;
        sgy[j] = xob[2 * j + 1];                    // xc_on[b, 0, j, 1]
    }
    __syncthreads();

    // ---- wave 0: mean of yc_off (fill value), kept in registers
    float fillv = 0.f;
    if (tid < 64) {
        float s = red[tid] + red[tid + 64] + red[tid + 128] + red[tid + 192];
        for (int o = 32; o > 0; o >>= 1) s += __shfl_down(s, o, 64);
        fillv = __shfl(s, 0, 64) / (float)NC;
    }

    // ---- per-thread top-3 scan over a 512-point slice
    const int q   = tid & (QPB - 1);
    const int sub = tid >> 6;
    const float* xtb = xt + (size_t)b * NTQ * 2;
    const float qx = xtb[2 * (qbase + q)];
    const float qy = xtb[2 * (qbase + q) + 1];

    float d0 = FMAXV, d1 = FMAXV, d2v = FMAXV;
    int   i0 = 0, i1 = 0, i2 = 0;
    const int kbeg = sub * CPS;
#pragma unroll 4
    for (int k = 0; k < CPS; ++k) {
        float2 p = spts[kbeg + k];          // wave-uniform LDS broadcast
        float dx = qx - p.x;
        float dy = qy - p.y;
        float dd = dx * dx + dy * dy;       // mul,mul,add — no FMA (contract off)
        if (dd < d2v) {                     // strict <: stable tie-break (lower idx first)
            int ki = kbeg + k;
            if (dd < d0)      { d2v = d1; i2 = i1; d1 = d0; i1 = i0; d0 = dd; i0 = ki; }
            else if (dd < d1) { d2v = d1; i2 = i1; d1 = dd; i1 = ki; }
            else              { d2v = dd; i2 = ki; }
        }
    }
    cd[sub][q][0] = d0;  cd[sub][q][1] = d1;  cd[sub][q][2] = d2v;
    ci[sub][q][0] = i0;  ci[sub][q][1] = i1;  ci[sub][q][2] = i2;
    __syncthreads();

    // ---- wave 0: merge 4x top-3 -> global top-3, then finalize the query
    if (tid < QPB) {
        float D0 = FMAXV, D1 = FMAXV, D2 = FMAXV;
        int   I0 = 0, I1 = 0, I2 = 0;
        for (int s = 0; s < SUBS; ++s) {
            for (int j = 0; j < 3; ++j) {
                float d = cd[s][tid][j];
                int   i = ci[s][tid][j];
                bool lt2 = (d < D2) || (d == D2 && i < I2);
                if (lt2) {
                    bool lt0 = (d < D0) || (d == D0 && i < I0);
                    bool lt1 = (d < D1) || (d == D1 && i < I1);
                    if (lt0)      { D2 = D1; I2 = I1; D1 = D0; I1 = I0; D0 = d; I0 = i; }
                    else if (lt1) { D2 = D1; I2 = I1; D1 = d; I1 = i; }
                    else          { D2 = d; I2 = i; }
                }
            }
        }

        // barycentric interpolation in the (nearest-3) triangle
        float2 pa = spts[I0], pb = spts[I1], pc = spts[I2];
        float e1x = pb.x - pa.x, e1y = pb.y - pa.y;
        float e2x = pc.x - pa.x, e2y = pc.y - pa.y;
        float rx  = qx - pa.x,   ry  = qy - pa.y;
        float det = e1x * e2y - e1y * e2x;
        float adet = fabsf(det);
        float det_safe = (adet < EPSF) ? 1.0f : det;
        float w1 = (rx * e2y - ry * e2x) / det_safe;
        float w2 = (e1x * ry - e1y * rx) / det_safe;
        float w0 = 1.0f - w1 - w2;
        bool inside = (w0 >= -EPSF) && (w1 >= -EPSF) && (w2 >= -EPSF) && (adet >= EPSF);
        float interp = w0 * sval[I0] + w1 * sval[I1] + w2 * sval[I2];
        float yt_offv = inside ? interp : fillv;

        // on-grid bilinear (searchsorted replicated: ix = clip(ss-1, 0, H-2))
        int ix = (int)((qx + 1.0f) * 63.5f);
        ix = min(max(ix, 0), HH - 2);
        while (ix > 0 && !(sgx[ix] < qx)) --ix;
        while (ix < HH - 2 && sgx[ix + 1] < qx) ++ix;
        int iy = (int)((qy + 1.0f) * 63.5f);
        iy = min(max(iy, 0), WW - 2);
        while (iy > 0 && !(sgy[iy] < qy)) --iy;
        while (iy < WW - 2 && sgy[iy + 1] < qy) ++iy;

        float x0 = sgx[ix], x1 = sgx[ix + 1];
        float y0 = sgy[iy], y1 = sgy[iy + 1];
        float tx = (qx - x0) / (x1 - x0);
        float ty = (qy - y0) / (y1 - y0);

        const float* yob = yc_on + (size_t)b * HH * WW;
        float v00 = yob[ix * WW + iy];
        float v01 = yob[ix * WW + iy + 1];
        float v10 = yob[(ix + 1) * WW + iy];
        float v11 = yob[(ix + 1) * WW + iy + 1];
        float yt_onv = v00 * (1.f - tx) * (1.f - ty)
                     + v10 * tx * (1.f - ty)
                     + v01 * (1.f - tx) * ty
                     + v11 * tx * ty;
        // xt in [-1,1) and grid spans [-1,1] inclusive -> on-grid 'inside' is
        // always true; the on-grid mean-fill path is unreachable.

        out[(size_t)b * NTQ + qbase + tid] =
            yt_offv * mix_w[0] + yt_onv * mix_w[1] + mix_b[0];
    }
}

extern "C" void kernel_launch(void* const* d_in, const int* in_sizes, int n_in,
                              void* d_out, int out_size, void* d_ws, size_t ws_size,
                              hipStream_t stream) {
    const float* xc_off = (const float*)d_in[0];
    const float* yc_off = (const float*)d_in[1];
    const float* xc_on  = (const float*)d_in[2];
    const float* yc_on  = (const float*)d_in[3];
    const float* xt     = (const float*)d_in[4];
    const float* mix_w  = (const float*)d_in[5];
    const float* mix_b  = (const float*)d_in[6];
    float* out = (float*)d_out;

    dim3 grid(NB * (NTQ / QPB));   // 8 * 64 = 512 blocks
    dim3 block(BLK);
    interp_enc_kernel<<<grid, block, 0, stream>>>(
        xc_off, yc_off, xc_on, yc_on, xt, mix_w, mix_b, out);
}

// Round 2
// 28.807 us; speedup vs baseline: 2.0801x; 2.0801x over previous
//
#include <hip/hip_runtime.h>
#include <math.h>

#define NB   8
#define NC   2048
#define HH   128
#define WW   128
#define NTQ  4096
#define EPSF 1e-6f
#define GC   16
#define CELLW 0.125f
#define FMAXV 3.402823466e+38f
#define IMAXV 0x7fffffff

// d_ws layout
#define WS_PTS  0                               // NB*NC float4 (px,py,val,idx_bits)
#define WS_OFF  (NB * NC * 16)                  // NB * 257 ints
#define WS_MEAN (WS_OFF + NB * (GC*GC + 1) * 4) // NB floats
#define WS_NEED (WS_MEAN + NB * 4)

// exact (d, idx) lexicographic insert into a sorted-3 set; strict total order
__device__ __forceinline__ void ins3(float d, int i,
                                     float& D0, int& I0, float& D1, int& I1,
                                     float& D2, int& I2) {
    bool lt2 = (d < D2) || (d == D2 && i < I2);
    bool lt1 = (d < D1) || (d == D1 && i < I1);
    bool lt0 = (d < D0) || (d == D0 && i < I0);
    D2 = lt1 ? D1 : (lt2 ? d : D2);  I2 = lt1 ? I1 : (lt2 ? i : I2);
    D1 = lt0 ? D0 : (lt1 ? d : D1);  I1 = lt0 ? I0 : (lt1 ? i : I1);
    D0 = lt0 ? d  : D0;              I0 = lt0 ? i  : I0;
}

// shared epilogue: barycentric (3-NN triangle) + on-grid bilinear + mix
__device__ __forceinline__ float finalize_query(
    float qx, float qy, int J0, int J1, int J2, int b, float fillv,
    const float* __restrict__ xc_off, const float* __restrict__ yc_off,
    const float* __restrict__ xc_on,  const float* __restrict__ yc_on,
    const float* __restrict__ mw, const float* __restrict__ mb)
{
#pragma clang fp contract(off)
    const float* xcb = xc_off + (size_t)b * NC * 2;
    const float* ycb = yc_off + (size_t)b * NC;
    float ax = xcb[2*J0], ay = xcb[2*J0+1];
    float bx = xcb[2*J1], by = xcb[2*J1+1];
    float cx = xcb[2*J2], cy = xcb[2*J2+1];
    float e1x = bx - ax, e1y = by - ay;
    float e2x = cx - ax, e2y = cy - ay;
    float rx  = qx - ax, ry  = qy - ay;
    float det = e1x * e2y - e1y * e2x;
    float adet = fabsf(det);
    float dets = (adet < EPSF) ? 1.0f : det;
    float w1 = (rx * e2y - ry * e2x) / dets;
    float w2 = (e1x * ry - e1y * rx) / dets;
    float w0 = 1.0f - w1 - w2;
    bool inside = (w0 >= -EPSF) && (w1 >= -EPSF) && (w2 >= -EPSF) && (adet >= EPSF);
    float interp = w0 * ycb[J0] + w1 * ycb[J1] + w2 * ycb[J2];
    float yoff = inside ? interp : fillv;

    const float* xob = xc_on + (size_t)b * HH * WW * 2; // gx[i]=xob[i*256], gy[j]=xob[2j+1]
    int ix = (int)((qx + 1.0f) * 63.5f);
    ix = min(max(ix, 0), HH - 2);
    while (ix > 0 && !(xob[(size_t)ix * 256] < qx)) --ix;
    while (ix < HH - 2 && xob[(size_t)(ix + 1) * 256] < qx) ++ix;
    int iy = (int)((qy + 1.0f) * 63.5f);
    iy = min(max(iy, 0), WW - 2);
    while (iy > 0 && !(xob[2 * iy + 1] < qy)) --iy;
    while (iy < WW - 2 && xob[2 * (iy + 1) + 1] < qy) ++iy;

    float x0 = xob[(size_t)ix * 256], x1 = xob[(size_t)(ix + 1) * 256];
    float y0 = xob[2 * iy + 1],       y1 = xob[2 * (iy + 1) + 1];
    float tx = (qx - x0) / (x1 - x0);
    float ty = (qy - y0) / (y1 - y0);
    const float* yob = yc_on + (size_t)b * HH * WW;
    float v00 = yob[ix * WW + iy];
    float v01 = yob[ix * WW + iy + 1];
    float v10 = yob[(ix + 1) * WW + iy];
    float v11 = yob[(ix + 1) * WW + iy + 1];
    float yon = v00 * (1.f - tx) * (1.f - ty)
              + v10 * tx * (1.f - ty)
              + v01 * (1.f - tx) * ty
              + v11 * tx * ty;
    return yoff * mw[0] + yon * mw[1] + mb[0];
}

// ---------------- Kernel A: per-batch CSR cell build (8 blocks) ----------------
__global__ __launch_bounds__(512) void build_cells_kernel(
    const float* __restrict__ xc_off, const float* __restrict__ yc_off,
    float4* __restrict__ wpts, int* __restrict__ woffs, float* __restrict__ wmean)
{
    __shared__ int   hist[256];
    __shared__ int   offs[257];
    __shared__ int   cursor[256];
    __shared__ float red[512];
    const int tid = threadIdx.x;
    const int b   = blockIdx.x;
    if (tid < 256) hist[tid] = 0;
    __syncthreads();

    const float2* xcb = (const float2*)(xc_off + (size_t)b * NC * 2);
    const float*  ycb = yc_off + (size_t)b * NC;
    float2 p[4]; float v[4]; int cell[4];
    float vsum = 0.f;
    for (int t = 0; t < 4; ++t) {
        int k = tid + t * 512;
        float2 q = xcb[k];
        p[t] = q; v[t] = ycb[k];
        int cx = (int)floorf((q.x + 1.0f) * 8.0f); cx = min(max(cx, 0), 15);
        int cy = (int)floorf((q.y + 1.0f) * 8.0f); cy = min(max(cy, 0), 15);
        cell[t] = cy * 16 + cx;
        atomicAdd(&hist[cell[t]], 1);
        vsum += v[t];
    }
    red[tid] = vsum;
    __syncthreads();

    if (tid < 64) {  // wave 0: exclusive scan of 256 cells
        int h0 = hist[4*tid], h1 = hist[4*tid+1], h2 = hist[4*tid+2], h3 = hist[4*tid+3];
        int s = h0 + h1 + h2 + h3; int tot = s;
        for (int off = 1; off < 64; off <<= 1) {
            int u = __shfl_up(s, off);
            if (tid >= off) s += u;
        }
        int excl = s - tot;
        offs[4*tid]   = excl;
        offs[4*tid+1] = excl + h0;
        offs[4*tid+2] = excl + h0 + h1;
        offs[4*tid+3] = excl + h0 + h1 + h2;
        if (tid == 63) offs[256] = excl + tot;  // == NC
    }
    __syncthreads();
    if (tid < 256) cursor[tid] = offs[tid];
    __syncthreads();

    for (int t = 0; t < 4; ++t) {
        int k = tid + t * 512;
        int pos = atomicAdd(&cursor[cell[t]], 1);
        float4 o; o.x = p[t].x; o.y = p[t].y; o.z = v[t]; o.w = __int_as_float(k);
        wpts[(size_t)b * NC + pos] = o;
    }
    if (tid < 257) woffs[b * 257 + tid] = offs[tid];
    __syncthreads();
    for (int s = 256; s > 0; s >>= 1) {
        if (tid < s) red[tid] += red[tid + s];
        __syncthreads();
    }
    if (tid == 0) wmean[b] = red[0] / (float)NC;
}

// ------------- Kernel B: 8 lanes/query ring search + epilogue (1024 blocks) -------------
__global__ __launch_bounds__(256) void interp_cells_kernel(
    const float4* __restrict__ wpts, const int* __restrict__ woffs,
    const float* __restrict__ wmean,
    const float* __restrict__ xc_off, const float* __restrict__ yc_off,
    const float* __restrict__ xc_on,  const float* __restrict__ yc_on,
    const float* __restrict__ xt, const float* __restrict__ mw,
    const float* __restrict__ mb, float* __restrict__ out)
{
#pragma clang fp contract(off)
    const int tid = threadIdx.x;
    const int g   = tid & 7;         // lane within query group
    const int grp = tid >> 3;        // 0..31
    const int b   = blockIdx.x >> 7; // 128 blocks per batch
    const int q   = (blockIdx.x & 127) * 32 + grp;

    const float qx = xt[((size_t)b * NTQ + q) * 2];
    const float qy = xt[((size_t)b * NTQ + q) * 2 + 1];
    int qcx = (int)floorf((qx + 1.0f) * 8.0f); qcx = min(max(qcx, 0), 15);
    int qcy = (int)floorf((qy + 1.0f) * 8.0f); qcy = min(max(qcy, 0), 15);

    const float4* pts  = wpts + (size_t)b * NC;
    const int*    offs = woffs + b * 257;

    float P0 = FMAXV, P1 = FMAXV, P2 = FMAXV;
    int   J0 = IMAXV, J1 = IMAXV, J2 = IMAXV;
    float F0 = FMAXV, F1 = FMAXV, F2 = FMAXV;
    int   G0 = IMAXV, G1 = IMAXV, G2 = IMAXV;

    // rings 0..1 (9 cells), lane g takes positions g and g+8
    for (int pp = g; pp < 9; pp += 8) {
        int cx = qcx + pp % 3 - 1, cy = qcy + pp / 3 - 1;
        if (cx < 0 || cx > 15 || cy < 0 || cy > 15) continue;
        int c = cy * 16 + cx;
        int s = offs[c], e = offs[c + 1];
        for (int k = s; k < e; ++k) {
            float4 p = pts[k];
            float dx = qx - p.x, dy = qy - p.y;
            float dd = dx * dx + dy * dy;      // exact: mul,mul,add (contract off)
            ins3(dd, __float_as_int(p.w), F0, G0, F1, G1, F2, G2);
        }
    }
    // butterfly-merge fresh candidates (disjoint across lanes), fold into persistent
    for (int m = 1; m <= 4; m <<= 1) {
        float e0 = __shfl_xor(F0, m), e1 = __shfl_xor(F1, m), e2 = __shfl_xor(F2, m);
        int   f0 = __shfl_xor(G0, m), f1 = __shfl_xor(G1, m), f2 = __shfl_xor(G2, m);
        ins3(e0, f0, F0, G0, F1, G1, F2, G2);
        ins3(e1, f1, F0, G0, F1, G1, F2, G2);
        ins3(e2, f2, F0, G0, F1, G1, F2, G2);
    }
    ins3(F0, G0, P0, J0, P1, J1, P2, J2);
    ins3(F1, G1, P0, J0, P1, J1, P2, J2);
    ins3(F2, G2, P0, J0, P1, J1, P2, J2);

    float bnd = 1.0f * CELLW - 1e-6f;   // unscanned (ring>=2) points have d >= 0.125 - slack
    bool done = P2 < bnd * bnd;

    for (int r = 2; r <= 15; ++r) {
        if (__all(done)) break;
        if (!done) {   // group-uniform
            F0 = F1 = F2 = FMAXV; G0 = G1 = G2 = IMAXV;
            for (int t = g; t < 8 * r; t += 8) {
                int side = t / (2 * r), u = t % (2 * r);
                int dx, dy;
                if (side == 0)      { dx = -r + u; dy = -r; }
                else if (side == 1) { dx = r;      dy = -r + u; }
                else if (side == 2) { dx = r - u;  dy = r; }
                else                { dx = -r;     dy = r - u; }
                int cx = qcx + dx, cy = qcy + dy;
                if (cx < 0 || cx > 15 || cy < 0 || cy > 15) continue;
                int c = cy * 16 + cx;
                int s = offs[c], e = offs[c + 1];
                for (int k = s; k < e; ++k) {
                    float4 p = pts[k];
                    float ddx = qx - p.x, ddy = qy - p.y;
                    float dd = ddx * ddx + ddy * ddy;
                    ins3(dd, __float_as_int(p.w), F0, G0, F1, G1, F2, G2);
                }
            }
            for (int m = 1; m <= 4; m <<= 1) {
                float e0 = __shfl_xor(F0, m), e1 = __shfl_xor(F1, m), e2 = __shfl_xor(F2, m);
                int   f0 = __shfl_xor(G0, m), f1 = __shfl_xor(G1, m), f2 = __shfl_xor(G2, m);
                ins3(e0, f0, F0, G0, F1, G1, F2, G2);
                ins3(e1, f1, F0, G0, F1, G1, F2, G2);
                ins3(e2, f2, F0, G0, F1, G1, F2, G2);
            }
            ins3(F0, G0, P0, J0, P1, J1, P2, J2);
            ins3(F1, G1, P0, J0, P1, J1, P2, J2);
            ins3(F2, G2, P0, J0, P1, J1, P2, J2);
            float bb = (float)r * CELLW - 1e-6f;
            done = P2 < bb * bb;
        }
    }

    if (g == 0) {
        out[(size_t)b * NTQ + q] = finalize_query(
            qx, qy, J0, J1, J2, b, wmean[b],
            xc_off, yc_off, xc_on, yc_on, mw, mb);
    }
}

// ---------------- Fallback: brute force (only if ws_size too small) ----------------
__global__ __launch_bounds__(256) void brute_kernel(
    const float* __restrict__ xc_off, const float* __restrict__ yc_off,
    const float* __restrict__ xc_on,  const float* __restrict__ yc_on,
    const float* __restrict__ xt, const float* __restrict__ mw,
    const float* __restrict__ mb, float* __restrict__ out)
{
#pragma clang fp contract(off)
    int qg = blockIdx.x * 256 + threadIdx.x;  // 0..32767
    int b = qg >> 12, q = qg & 4095;
    const float2* xcb = (const float2*)(xc_off + (size_t)b * NC * 2);
    const float*  ycb = yc_off + (size_t)b * NC;
    float qx = xt[((size_t)b * NTQ + q) * 2];
    float qy = xt[((size_t)b * NTQ + q) * 2 + 1];
    float D0 = FMAXV, D1 = FMAXV, D2 = FMAXV;
    int   I0 = IMAXV, I1 = IMAXV, I2 = IMAXV;
    float vs = 0.f;
    for (int k = 0; k < NC; ++k) {
        float2 p = xcb[k];
        vs += ycb[k];
        float dx = qx - p.x, dy = qy - p.y;
        float dd = dx * dx + dy * dy;
        ins3(dd, k, D0, I0, D1, I1, D2, I2);
    }
    out[(size_t)b * NTQ + q] = finalize_query(
        qx, qy, I0, I1, I2, b, vs / (float)NC,
        xc_off, yc_off, xc_on, yc_on, mw, mb);
}

extern "C" void kernel_launch(void* const* d_in, const int* in_sizes, int n_in,
                              void* d_out, int out_size, void* d_ws, size_t ws_size,
                              hipStream_t stream) {
    const float* xc_off = (const float*)d_in[0];
    const float* yc_off = (const float*)d_in[1];
    const float* xc_on  = (const float*)d_in[2];
    const float* yc_on  = (const float*)d_in[3];
    const float* xt     = (const float*)d_in[4];
    const float* mix_w  = (const float*)d_in[5];
    const float* mix_b  = (const float*)d_in[6];
    float* out = (float*)d_out;

    if (ws_size >= (size_t)WS_NEED) {
        float4* wpts  = (float4*)((char*)d_ws + WS_PTS);
        int*    woffs = (int*)((char*)d_ws + WS_OFF);
        float*  wmean = (float*)((char*)d_ws + WS_MEAN);
        build_cells_kernel<<<NB, 512, 0, stream>>>(xc_off, yc_off, wpts, woffs, wmean);
        interp_cells_kernel<<<1024, 256, 0, stream>>>(
            wpts, woffs, wmean, xc_off, yc_off, xc_on, yc_on, xt, mix_w, mix_b, out);
    } else {
        brute_kernel<<<128, 256, 0, stream>>>(
            xc_off, yc_off, xc_on, yc_on, xt, mix_w, mix_b, out);
    }
}

// Round 3
// 24.143 us; speedup vs baseline: 2.4819x; 1.1932x over previous
//
#include <hip/hip_runtime.h>
#include <math.h>

#define NB   8
#define NC   2048
#define HH   128
#define WW   128
#define NTQ  4096
#define EPSF 1e-6f
#define CELLW 0.125f
#define FMAXV 3.402823466e+38f
#define IMAXV 0x7fffffff
#define BLK  512
#define QPB  64          // queries per block (8 lanes per query)

// exact (d, idx) lexicographic insert into sorted-3; payload: idx (tie-break) + pos (LDS lookup)
__device__ __forceinline__ void ins3(float d, int i, int s,
    float& D0, int& I0, int& S0,
    float& D1, int& I1, int& S1,
    float& D2, int& I2, int& S2)
{
    bool lt2 = (d < D2) || (d == D2 && i < I2);
    bool lt1 = (d < D1) || (d == D1 && i < I1);
    bool lt0 = (d < D0) || (d == D0 && i < I0);
    D2 = lt1 ? D1 : (lt2 ? d : D2);  I2 = lt1 ? I1 : (lt2 ? i : I2);  S2 = lt1 ? S1 : (lt2 ? s : S2);
    D1 = lt0 ? D0 : (lt1 ? d : D1);  I1 = lt0 ? I0 : (lt1 ? i : I1);  S1 = lt0 ? S0 : (lt1 ? s : S1);
    D0 = lt0 ? d  : D0;              I0 = lt0 ? i  : I0;              S0 = lt0 ? s  : S0;
}

__global__ __launch_bounds__(BLK) void fused_interp_kernel(
    const float* __restrict__ xc_off,  // (B,NC,2)
    const float* __restrict__ yc_off,  // (B,NC,1)
    const float* __restrict__ xc_on,   // (B,H,W,2)
    const float* __restrict__ yc_on,   // (B,H,W,1)
    const float* __restrict__ xt,      // (B,NT,2)
    const float* __restrict__ mw,      // (2,1)
    const float* __restrict__ mb,      // (1,)
    float* __restrict__ out)           // (B,NT,1)
{
#pragma clang fp contract(off)
    __shared__ float4 spts[NC];      // 32 KB: (x, y, val, orig_idx bits), CSR-ordered
    __shared__ int    shist[256];
    __shared__ int    soffs[257];
    __shared__ int    scur[256];
    __shared__ float  sgx[HH];
    __shared__ float  sgy[WW];
    __shared__ float  sred[8];

    const int tid   = threadIdx.x;
    const int b     = blockIdx.x >> 6;          // 64 blocks per batch
    const int qbase = (blockIdx.x & 63) * QPB;

    // ---- zero hist + stage grid axes
    if (tid < 256) shist[tid] = 0;
    const float* xob = xc_on + (size_t)b * HH * WW * 2;
    if (tid >= 256 && tid < 256 + HH) sgx[tid - 256] = xob[(size_t)(tid - 256) * (WW * 2)];
    if (tid >= 384 && tid < 384 + WW) sgy[tid - 384] = xob[2 * (tid - 384) + 1];
    __syncthreads();

    // ---- read context points, histogram cells, partial value-sum
    const float2* xcb = (const float2*)(xc_off + (size_t)b * NC * 2);
    const float*  ycb = yc_off + (size_t)b * NC;
    float2 pp_[4]; float vv_[4]; int cc_[4];
    float vsum = 0.f;
#pragma unroll
    for (int t = 0; t < 4; ++t) {
        int k = tid + t * BLK;
        float2 P = xcb[k];
        float  V = ycb[k];
        pp_[t] = P; vv_[t] = V;
        int cx = (int)floorf((P.x + 1.0f) * 8.0f); cx = min(max(cx, 0), 15);
        int cy = (int)floorf((P.y + 1.0f) * 8.0f); cy = min(max(cy, 0), 15);
        cc_[t] = cy * 16 + cx;
        atomicAdd(&shist[cc_[t]], 1);
        vsum += V;
    }
    for (int o = 32; o > 0; o >>= 1) vsum += __shfl_down(vsum, o);
    if ((tid & 63) == 0) sred[tid >> 6] = vsum;
    __syncthreads();

    // ---- wave 0: exclusive scan of 256 cell counts
    if (tid < 64) {
        int h0 = shist[4*tid], h1 = shist[4*tid+1], h2 = shist[4*tid+2], h3 = shist[4*tid+3];
        int s = h0 + h1 + h2 + h3; int tot = s;
        for (int off = 1; off < 64; off <<= 1) {
            int u = __shfl_up(s, off);
            if (tid >= off) s += u;
        }
        int excl = s - tot;
        soffs[4*tid]   = excl;
        soffs[4*tid+1] = excl + h0;
        soffs[4*tid+2] = excl + h0 + h1;
        soffs[4*tid+3] = excl + h0 + h1 + h2;
        if (tid == 63) soffs[256] = excl + tot;   // == NC
    }
    __syncthreads();
    if (tid < 256) scur[tid] = soffs[tid];
    __syncthreads();

    // ---- scatter into CSR order in LDS
#pragma unroll
    for (int t = 0; t < 4; ++t) {
        int k = tid + t * BLK;
        int pos = atomicAdd(&scur[cc_[t]], 1);
        float4 o4; o4.x = pp_[t].x; o4.y = pp_[t].y; o4.z = vv_[t]; o4.w = __int_as_float(k);
        spts[pos] = o4;
    }
    __syncthreads();

    const float fillv = (sred[0] + sred[1] + sred[2] + sred[3] +
                         sred[4] + sred[5] + sred[6] + sred[7]) / (float)NC;

    // ---- 8-lane ring search per query (all candidate reads from LDS)
    const int g   = tid & 7;
    const int grp = tid >> 3;        // 0..63
    const int q   = qbase + grp;
    const float qx = xt[((size_t)b * NTQ + q) * 2];
    const float qy = xt[((size_t)b * NTQ + q) * 2 + 1];
    int qcx = (int)floorf((qx + 1.0f) * 8.0f); qcx = min(max(qcx, 0), 15);
    int qcy = (int)floorf((qy + 1.0f) * 8.0f); qcy = min(max(qcy, 0), 15);

    float P0 = FMAXV, P1 = FMAXV, P2 = FMAXV;
    int   J0 = IMAXV, J1 = IMAXV, J2 = IMAXV;
    int   S0 = 0,     S1 = 0,     S2 = 0;
    float F0 = FMAXV, F1 = FMAXV, F2 = FMAXV;
    int   G0 = IMAXV, G1 = IMAXV, G2 = IMAXV;
    int   T0 = 0,     T1 = 0,     T2 = 0;

    // rings 0..1 (9 cells): lane g takes positions g and g+8 (disjoint per lane)
    for (int pp = g; pp < 9; pp += 8) {
        int cx = qcx + pp % 3 - 1, cy = qcy + pp / 3 - 1;
        if (cx < 0 || cx > 15 || cy < 0 || cy > 15) continue;
        int c = cy * 16 + cx;
        int s = soffs[c], e = soffs[c + 1];
        for (int k = s; k < e; ++k) {
            float4 P = spts[k];
            float dx = qx - P.x, dy = qy - P.y;
            float dd = dx * dx + dy * dy;        // mul,mul,add — contract off
            ins3(dd, __float_as_int(P.w), k, F0, G0, T0, F1, G1, T1, F2, G2, T2);
        }
    }
    // butterfly merge (disjoint source sets at every round)
    for (int m = 1; m <= 4; m <<= 1) {
        float e0 = __shfl_xor(F0, m), e1 = __shfl_xor(F1, m), e2 = __shfl_xor(F2, m);
        int   f0 = __shfl_xor(G0, m), f1 = __shfl_xor(G1, m), f2 = __shfl_xor(G2, m);
        int   t0 = __shfl_xor(T0, m), t1 = __shfl_xor(T1, m), t2 = __shfl_xor(T2, m);
        ins3(e0, f0, t0, F0, G0, T0, F1, G1, T1, F2, G2, T2);
        ins3(e1, f1, t1, F0, G0, T0, F1, G1, T1, F2, G2, T2);
        ins3(e2, f2, t2, F0, G0, T0, F1, G1, T1, F2, G2, T2);
    }
    ins3(F0, G0, T0, P0, J0, S0, P1, J1, S1, P2, J2, S2);
    ins3(F1, G1, T1, P0, J0, S0, P1, J1, S1, P2, J2, S2);
    ins3(F2, G2, T2, P0, J0, S0, P1, J1, S1, P2, J2, S2);

    float bnd = 1.0f * CELLW - 1e-6f;
    bool done = P2 < bnd * bnd;

    for (int r = 2; r <= 15; ++r) {
        if (__all(done)) break;
        if (!done) {                 // group-uniform predicate
            F0 = F1 = F2 = FMAXV; G0 = G1 = G2 = IMAXV; T0 = T1 = T2 = 0;
            for (int t = g; t < 8 * r; t += 8) {
                int side = t / (2 * r), u = t % (2 * r);
                int dx, dy;
                if (side == 0)      { dx = -r + u; dy = -r; }
                else if (side == 1) { dx = r;      dy = -r + u; }
                else if (side == 2) { dx = r - u;  dy = r; }
                else                { dx = -r;     dy = r - u; }
                int cx = qcx + dx, cy = qcy + dy;
                if (cx < 0 || cx > 15 || cy < 0 || cy > 15) continue;
                int c = cy * 16 + cx;
                int s = soffs[c], e = soffs[c + 1];
                for (int k = s; k < e; ++k) {
                    float4 P = spts[k];
                    float ddx = qx - P.x, ddy = qy - P.y;
                    float dd = ddx * ddx + ddy * ddy;
                    ins3(dd, __float_as_int(P.w), k, F0, G0, T0, F1, G1, T1, F2, G2, T2);
                }
            }
            for (int m = 1; m <= 4; m <<= 1) {
                float e0 = __shfl_xor(F0, m), e1 = __shfl_xor(F1, m), e2 = __shfl_xor(F2, m);
                int   f0 = __shfl_xor(G0, m), f1 = __shfl_xor(G1, m), f2 = __shfl_xor(G2, m);
                int   t0 = __shfl_xor(T0, m), t1 = __shfl_xor(T1, m), t2 = __shfl_xor(T2, m);
                ins3(e0, f0, t0, F0, G0, T0, F1, G1, T1, F2, G2, T2);
                ins3(e1, f1, t1, F0, G0, T0, F1, G1, T1, F2, G2, T2);
                ins3(e2, f2, t2, F0, G0, T0, F1, G1, T1, F2, G2, T2);
            }
            ins3(F0, G0, T0, P0, J0, S0, P1, J1, S1, P2, J2, S2);
            ins3(F1, G1, T1, P0, J0, S0, P1, J1, S1, P2, J2, S2);
            ins3(F2, G2, T2, P0, J0, S0, P1, J1, S1, P2, J2, S2);
            float bb = (float)r * CELLW - 1e-6f;
            done = P2 < bb * bb;
        }
    }

    // ---- epilogue on lane g==0 (points/vals from LDS, grid axes from LDS)
    if (g == 0) {
        float4 A = spts[S0], Bp = spts[S1], C = spts[S2];
        float e1x = Bp.x - A.x, e1y = Bp.y - A.y;
        float e2x = C.x  - A.x, e2y = C.y  - A.y;
        float rx  = qx - A.x,   ry  = qy - A.y;
        float det = e1x * e2y - e1y * e2x;
        float adet = fabsf(det);
        float dets = (adet < EPSF) ? 1.0f : det;
        float w1 = (rx * e2y - ry * e2x) / dets;
        float w2 = (e1x * ry - e1y * rx) / dets;
        float w0 = 1.0f - w1 - w2;
        bool inside = (w0 >= -EPSF) && (w1 >= -EPSF) && (w2 >= -EPSF) && (adet >= EPSF);
        float interp = w0 * A.z + w1 * Bp.z + w2 * C.z;
        float yoff = inside ? interp : fillv;

        // on-grid bilinear (searchsorted: ix = clip(ss-1, 0, H-2); fix-up vs LDS axes)
        int ix = (int)((qx + 1.0f) * 63.5f);
        ix = min(max(ix, 0), HH - 2);
        while (ix > 0 && !(sgx[ix] < qx)) --ix;
        while (ix < HH - 2 && sgx[ix + 1] < qx) ++ix;
        int iy = (int)((qy + 1.0f) * 63.5f);
        iy = min(max(iy, 0), WW - 2);
        while (iy > 0 && !(sgy[iy] < qy)) --iy;
        while (iy < WW - 2 && sgy[iy + 1] < qy) ++iy;

        float x0 = sgx[ix], x1 = sgx[ix + 1];
        float y0 = sgy[iy], y1 = sgy[iy + 1];
        float tx = (qx - x0) / (x1 - x0);
        float ty = (qy - y0) / (y1 - y0);
        const float* yob = yc_on + (size_t)b * HH * WW;
        float v00 = yob[ix * WW + iy];
        float v01 = yob[ix * WW + iy + 1];
        float v10 = yob[(ix + 1) * WW + iy];
        float v11 = yob[(ix + 1) * WW + iy + 1];
        float yon = v00 * (1.f - tx) * (1.f - ty)
                  + v10 * tx * (1.f - ty)
                  + v01 * (1.f - tx) * ty
                  + v11 * tx * ty;
        // xt in [-1,1), grid spans [-1,1] -> on-grid fill path unreachable

        out[(size_t)b * NTQ + q] = yoff * mw[0] + yon * mw[1] + mb[0];
    }
}

extern "C" void kernel_launch(void* const* d_in, const int* in_sizes, int n_in,
                              void* d_out, int out_size, void* d_ws, size_t ws_size,
                              hipStream_t stream) {
    const float* xc_off = (const float*)d_in[0];
    const float* yc_off = (const float*)d_in[1];
    const float* xc_on  = (const float*)d_in[2];
    const float* yc_on  = (const float*)d_in[3];
    const float* xt     = (const float*)d_in[4];
    const float* mix_w  = (const float*)d_in[5];
    const float* mix_b  = (const float*)d_in[6];
    float* out = (float*)d_out;

    fused_interp_kernel<<<NB * (NTQ / QPB), BLK, 0, stream>>>(
        xc_off, yc_off, xc_on, yc_on, xt, mix_w, mix_b, out);
}

// Round 4
// 12.779 us; speedup vs baseline: 4.6889x; 1.8892x over previous
//
#include <hip/hip_runtime.h>
#include <math.h>

#define NB   8
#define NC   2048
#define HH   128
#define WW   128
#define NTQ  4096
#define EPSF 1e-6f
#define CELLW 0.125f
#define BLK  512
#define QPB  128         // queries per block, 4 lanes per query
#define LPQ  4
#define UMAX 0xFFFFFFFFFFFFFFFFULL

typedef unsigned long long u64;

// branchless top-3 insert under u64 = (d2_bits<<32)|orig_idx lexicographic order
__device__ __forceinline__ void ins3u(u64 u, u64& U0, u64& U1, u64& U2) {
    bool lt2 = u < U2, lt1 = u < U1, lt0 = u < U0;
    U2 = lt1 ? U1 : (lt2 ? u : U2);
    U1 = lt0 ? U0 : (lt1 ? u : U1);
    U0 = lt0 ? u  : U0;
}

__global__ __launch_bounds__(BLK) void fused_interp_kernel(
    const float* __restrict__ xc_off,  // (B,NC,2)
    const float* __restrict__ yc_off,  // (B,NC,1)
    const float* __restrict__ xc_on,   // (B,H,W,2)
    const float* __restrict__ yc_on,   // (B,H,W,1)
    const float* __restrict__ xt,      // (B,NT,2)
    const float* __restrict__ mw,      // (2,1)
    const float* __restrict__ mb,      // (1,)
    float* __restrict__ out)           // (B,NT,1)
{
#pragma clang fp contract(off)
    __shared__ float4 spts[NC];      // 32 KB: (x, y, val, orig_idx bits), CSR order
    __shared__ int    shist[256];
    __shared__ int    soffs[257];
    __shared__ int    scur[256];
    __shared__ float  sgx[HH];
    __shared__ float  sgy[WW];
    __shared__ float  sred[8];

    const int tid   = threadIdx.x;
    const int b     = blockIdx.x >> 5;           // 32 blocks per batch
    const int qbase = (blockIdx.x & 31) * QPB;

    // ---- zero hist + stage grid axes
    if (tid < 256) shist[tid] = 0;
    const float* xob = xc_on + (size_t)b * HH * WW * 2;
    if (tid >= 256 && tid < 256 + HH) sgx[tid - 256] = xob[(size_t)(tid - 256) * (WW * 2)];
    if (tid >= 384 && tid < 384 + WW) sgy[tid - 384] = xob[2 * (tid - 384) + 1];
    __syncthreads();

    // ---- read context, histogram cells, partial value-sum
    const float2* xcb = (const float2*)(xc_off + (size_t)b * NC * 2);
    const float*  ycb = yc_off + (size_t)b * NC;
    float2 pp_[4]; float vv_[4]; int cc_[4];
    float vsum = 0.f;
#pragma unroll
    for (int t = 0; t < 4; ++t) {
        int k = tid + t * BLK;
        float2 P = xcb[k];
        float  V = ycb[k];
        pp_[t] = P; vv_[t] = V;
        int cx = (int)floorf((P.x + 1.0f) * 8.0f); cx = min(max(cx, 0), 15);
        int cy = (int)floorf((P.y + 1.0f) * 8.0f); cy = min(max(cy, 0), 15);
        cc_[t] = cy * 16 + cx;
        atomicAdd(&shist[cc_[t]], 1);
        vsum += V;
    }
    for (int o = 32; o > 0; o >>= 1) vsum += __shfl_down(vsum, o);
    if ((tid & 63) == 0) sred[tid >> 6] = vsum;
    __syncthreads();

    // ---- wave 0: exclusive scan of 256 cell counts
    if (tid < 64) {
        int h0 = shist[4*tid], h1 = shist[4*tid+1], h2 = shist[4*tid+2], h3 = shist[4*tid+3];
        int s = h0 + h1 + h2 + h3; int tot = s;
        for (int off = 1; off < 64; off <<= 1) {
            int u = __shfl_up(s, off);
            if (tid >= off) s += u;
        }
        int excl = s - tot;
        soffs[4*tid]   = excl;
        soffs[4*tid+1] = excl + h0;
        soffs[4*tid+2] = excl + h0 + h1;
        soffs[4*tid+3] = excl + h0 + h1 + h2;
        if (tid == 63) soffs[256] = excl + tot;   // == NC
    }
    __syncthreads();
    if (tid < 256) scur[tid] = soffs[tid];
    __syncthreads();

    // ---- scatter into CSR order in LDS
#pragma unroll
    for (int t = 0; t < 4; ++t) {
        int k = tid + t * BLK;
        int pos = atomicAdd(&scur[cc_[t]], 1);
        float4 o4; o4.x = pp_[t].x; o4.y = pp_[t].y; o4.z = vv_[t]; o4.w = __int_as_float(k);
        spts[pos] = o4;
    }
    __syncthreads();

    const float fillv = (sred[0] + sred[1] + sred[2] + sred[3] +
                         sred[4] + sred[5] + sred[6] + sred[7]) / (float)NC;

    // ---- 4-lane-per-query search; candidates from LDS, balanced over points
    const int g   = tid & (LPQ - 1);
    const int grp = tid >> 2;         // 0..127
    const int q   = qbase + grp;
    const float qx = xt[((size_t)b * NTQ + q) * 2];
    const float qy = xt[((size_t)b * NTQ + q) * 2 + 1];
    int qcx = (int)floorf((qx + 1.0f) * 8.0f); qcx = min(max(qcx, 0), 15);
    int qcy = (int)floorf((qy + 1.0f) * 8.0f); qcy = min(max(qcy, 0), 15);

    u64 P0 = UMAX, P1 = UMAX, P2 = UMAX;   // persistent top-3
    u64 F0 = UMAX, F1 = UMAX, F2 = UMAX;   // fresh candidates this round

    // rings 0..1: three contiguous CSR row-segments, lanes stride over points
    for (int row = 0; row < 3; ++row) {
        int cy = qcy + row - 1;
        if (cy < 0 || cy > 15) continue;
        int c0 = cy * 16 + max(qcx - 1, 0);
        int c1 = cy * 16 + min(qcx + 1, 15);
        int s = soffs[c0], e = soffs[c1 + 1];
        for (int k = s + g; k < e; k += LPQ) {
            float4 P = spts[k];
            float dx = qx - P.x, dy = qy - P.y;
            float dd = dx * dx + dy * dy;          // mul,mul,add — contract off
            u64 u = ((u64)__float_as_uint(dd) << 32) | (unsigned int)__float_as_int(P.w);
            ins3u(u, F0, F1, F2);
        }
    }
    // butterfly merge across the 4 lanes (disjoint sets each round)
    for (int m = 1; m <= 2; m <<= 1) {
        u64 e0 = __shfl_xor(F0, m), e1 = __shfl_xor(F1, m), e2 = __shfl_xor(F2, m);
        ins3u(e0, F0, F1, F2);
        ins3u(e1, F0, F1, F2);
        ins3u(e2, F0, F1, F2);
    }
    P0 = F0; P1 = F1; P2 = F2;

    float bnd = 1.0f * CELLW - 1e-6f;
    u64 thr = ((u64)__float_as_uint(bnd * bnd)) << 32;
    bool done = P2 < thr;

    for (int r = 2; r <= 15; ++r) {
        if (__all(done)) break;
        if (!done) {                  // group-uniform (P identical across the 4 lanes)
            F0 = F1 = F2 = UMAX;
            for (int t = g; t < 8 * r; t += LPQ) {
                int side = t / (2 * r), u = t % (2 * r);
                int dx, dy;
                if (side == 0)      { dx = -r + u; dy = -r; }
                else if (side == 1) { dx = r;      dy = -r + u; }
                else if (side == 2) { dx = r - u;  dy = r; }
                else                { dx = -r;     dy = r - u; }
                int cx = qcx + dx, cy = qcy + dy;
                if (cx < 0 || cx > 15 || cy < 0 || cy > 15) continue;
                int c = cy * 16 + cx;
                int s = soffs[c], e = soffs[c + 1];
                for (int k = s; k < e; ++k) {
                    float4 P = spts[k];
                    float ddx = qx - P.x, ddy = qy - P.y;
                    float dd = ddx * ddx + ddy * ddy;
                    u64 uu = ((u64)__float_as_uint(dd) << 32) | (unsigned int)__float_as_int(P.w);
                    ins3u(uu, F0, F1, F2);
                }
            }
            for (int m = 1; m <= 2; m <<= 1) {
                u64 e0 = __shfl_xor(F0, m), e1 = __shfl_xor(F1, m), e2 = __shfl_xor(F2, m);
                ins3u(e0, F0, F1, F2);
                ins3u(e1, F0, F1, F2);
                ins3u(e2, F0, F1, F2);
            }
            ins3u(F0, P0, P1, P2);
            ins3u(F1, P0, P1, P2);
            ins3u(F2, P0, P1, P2);
            float bb = (float)r * CELLW - 1e-6f;
            u64 tt = ((u64)__float_as_uint(bb * bb)) << 32;
            done = P2 < tt;
        }
    }

    // ---- epilogue on lane g==0 (triangle coords re-read from global, L2-hot)
    if (g == 0) {
        int J0 = (int)(P0 & 0xFFFFFFFFULL);
        int J1 = (int)(P1 & 0xFFFFFFFFULL);
        int J2 = (int)(P2 & 0xFFFFFFFFULL);
        float2 A  = xcb[J0];
        float2 Bp = xcb[J1];
        float2 C  = xcb[J2];
        float e1x = Bp.x - A.x, e1y = Bp.y - A.y;
        float e2x = C.x  - A.x, e2y = C.y  - A.y;
        float rx  = qx - A.x,   ry  = qy - A.y;
        float det = e1x * e2y - e1y * e2x;
        float adet = fabsf(det);
        float dets = (adet < EPSF) ? 1.0f : det;
        float w1 = (rx * e2y - ry * e2x) / dets;
        float w2 = (e1x * ry - e1y * rx) / dets;
        float w0 = 1.0f - w1 - w2;
        bool inside = (w0 >= -EPSF) && (w1 >= -EPSF) && (w2 >= -EPSF) && (adet >= EPSF);
        float interp = w0 * ycb[J0] + w1 * ycb[J1] + w2 * ycb[J2];
        float yoff = inside ? interp : fillv;

        // on-grid bilinear (searchsorted: ix = clip(ss-1, 0, H-2); fix-up vs LDS axes)
        int ix = (int)((qx + 1.0f) * 63.5f);
        ix = min(max(ix, 0), HH - 2);
        while (ix > 0 && !(sgx[ix] < qx)) --ix;
        while (ix < HH - 2 && sgx[ix + 1] < qx) ++ix;
        int iy = (int)((qy + 1.0f) * 63.5f);
        iy = min(max(iy, 0), WW - 2);
        while (iy > 0 && !(sgy[iy] < qy)) --iy;
        while (iy < WW - 2 && sgy[iy + 1] < qy) ++iy;

        float x0 = sgx[ix], x1 = sgx[ix + 1];
        float y0 = sgy[iy], y1 = sgy[iy + 1];
        float tx = (qx - x0) / (x1 - x0);
        float ty = (qy - y0) / (y1 - y0);
        const float* yob = yc_on + (size_t)b * HH * WW;
        float v00 = yob[ix * WW + iy];
        float v01 = yob[ix * WW + iy + 1];
        float v10 = yob[(ix + 1) * WW + iy];
        float v11 = yob[(ix + 1) * WW + iy + 1];
        float yon = v00 * (1.f - tx) * (1.f - ty)
                  + v10 * tx * (1.f - ty)
                  + v01 * (1.f - tx) * ty
                  + v11 * tx * ty;
        // xt in [-1,1), grid spans [-1,1] -> on-grid fill path unreachable

        out[(size_t)b * NTQ + q] = yoff * mw[0] + yon * mw[1] + mb[0];
    }
}

extern "C" void kernel_launch(void* const* d_in, const int* in_sizes, int n_in,
                              void* d_out, int out_size, void* d_ws, size_t ws_size,
                              hipStream_t stream) {
    const float* xc_off = (const float*)d_in[0];
    const float* yc_off = (const float*)d_in[1];
    const float* xc_on  = (const float*)d_in[2];
    const float* yc_on  = (const float*)d_in[3];
    const float* xt     = (const float*)d_in[4];
    const float* mix_w  = (const float*)d_in[5];
    const float* mix_b  = (const float*)d_in[6];
    float* out = (float*)d_out;

    fused_interp_kernel<<<NB * (NTQ / QPB), BLK, 0, stream>>>(
        xc_off, yc_off, xc_on, yc_on, xt, mix_w, mix_b, out);
}